// Round 10
// baseline (5498.539 us; speedup 1.0000x reference)
//
#include <hip/hip_runtime.h>

#define BB 32
#define TSRC 12
#define HORZ 12
#define NN 883
#define DD 10
#define HH 64
#define BN (BB*NN)     // 28256
#define BNP 28288      // 64-aligned stride
#define KF 4           // MFMA K=128: kk'=0..63 -> h/zh rows 0..63, 64..127 -> ax 0..63.
                       // x, bias, ax64 handled as exact fp32 rank-1 terms (W row = kk'+1).
#define NT 14          // ceil(NN/64) m-tiles per b
#define NST (TSRC+HORZ)

typedef __attribute__((ext_vector_type(8))) short short8;
typedef __attribute__((ext_vector_type(4))) float f32x4;

static __device__ __forceinline__ float sigmf(float x) { return 1.f/(1.f + __expf(-x)); }
static __device__ __forceinline__ float tanh_fast(float x) {
  float e = __expf(2.f*x);
  return (e - 1.f) / (e + 1.f);
}
static __device__ __forceinline__ unsigned int bf_hi(float f) {
  unsigned int u = __float_as_uint(f);
  return (u + 0x7fffu + ((u >> 16) & 1u)) >> 16;
}
static __device__ __forceinline__ float bf_f(unsigned int h) {
  return __uint_as_float(h << 16);
}

// XCD-chunked block swizzle: hw assigns wg->XCD by (linear id % 8); choose (b, rtile)
// so all NT tiles of one b share an XCD -> Xs/nv/W re-reads become L2 hits.
static __device__ __forceinline__ void swz_block(int& b, int& rt) {
  int lin = blockIdx.x + blockIdx.y*NT;
  int c = lin & 7, q = lin >> 3;
  b = c + ((q/NT) << 3);
  rt = q - (q/NT)*NT;
}

// Xs chunk layout (per (b, mtile), 16384 B = 8192 shorts):
//   logical short (hl, c, ms): byte = hl*8192 + c*128 + ms*2, stored at byte ^ ((c&7)<<4)
//   c=0 -> x column; c=1..63 -> h/zh rows 0..62. Row 63 kept as fp32 (h / zh63).
static __device__ __forceinline__ void xs_store(unsigned short* chunk, int c, int mm2, float v) {
  int p0 = (c*128 + (mm2 ^ ((c & 7) << 4))) >> 1;
  unsigned int hi = bf_hi(v);
  chunk[p0] = (unsigned short)hi;
  chunk[p0 + 4096] = (unsigned short)bf_hi(v - bf_f(hi));
}

// ---------------- prep_all: nvAll[24][10][BNP] once; x0 columns for step 0 ----------------
__global__ __launch_bounds__(256) void prep_all(
    const float* __restrict__ tidE1, const float* __restrict__ tidE2,
    const float* __restrict__ diwE1, const float* __restrict__ diwE2,
    const float* __restrict__ nodeE,
    const int* __restrict__ stid, const int* __restrict__ sdiw,
    const int* __restrict__ ttid, const int* __restrict__ tdiw,
    const float* __restrict__ xsrc,
    float* __restrict__ nv1A, float* __restrict__ nv2A,
    unsigned short* __restrict__ XsH, unsigned short* __restrict__ XsZ)
{
  int i = blockIdx.x*256 + threadIdx.x;
  if (i >= BN) return;
  int st = blockIdx.y;
  int b = i / NN, n = i - b*NN;
  const int* tix = (st < TSRC) ? stid : ttid;
  const int* dix = (st < TSRC) ? sdiw : tdiw;
  int t = (st < TSRC) ? st : st - TSRC;
  int gi = (b*TSRC + t)*NN + n;
  int ti = tix[gi]*DD, di = dix[gi]*DD;
  int nE = n*DD;
  float* nv1T = nv1A + (size_t)st*DD*BNP;
  float* nv2T = nv2A + (size_t)st*DD*BNP;
#pragma unroll
  for (int d = 0; d < DD; ++d) {
    float E = nodeE[nE+d];
    nv1T[d*BNP+i] = tanh_fast(E * (tidE1[ti+d] * diwE1[di+d]));
    nv2T[d*BNP+i] = tanh_fast(E * (tidE2[ti+d] * diwE2[di+d]));
  }
  if (st == 0) {
    float xv = xsrc[gi];
    size_t cb = ((size_t)(b*NT + (n >> 6)))*8192;
    int mm = n & 63;
    unsigned int hi = bf_hi(xv);
    unsigned short los = (unsigned short)bf_hi(xv - bf_f(hi));
    XsH[cb + mm] = (unsigned short)hi; XsH[cb + 4096 + mm] = los;
    XsZ[cb + mm] = (unsigned short)hi; XsZ[cb + 4096 + mm] = los;
  }
}

// ------- wsplit: W -> B-fragment-ordered split-bf16 Wf[d][hl][kf4][quad][NO][8] -------
// kk' = kf*32+quad*8+j in [0,128); W source row = kk'+1 (rows 1..128 = h|ax channels).
__global__ __launch_bounds__(256) void wsplit_kernel(
    const float* __restrict__ W, const float* __restrict__ bias,
    int NO, unsigned short* __restrict__ Wf)
{
  (void)bias;
  int i = blockIdx.x*256 + threadIdx.x;
  int total = DD*2*KF*4*NO*8;
  if (i >= total) return;
  int j = i & 7; int r = i >> 3;
  int o = r % NO; r /= NO;
  int quad = r & 3; r >>= 2;
  int kf = r & 3; r >>= 2;
  int hl = r & 1; int d = r >> 1;
  int kk = kf*32 + quad*8 + j;
  float v = W[(size_t)(d*130 + kk + 1)*NO + o];
  unsigned int hi = bf_hi(v);
  Wf[i] = (hl == 0) ? (unsigned short)hi : (unsigned short)bf_hi(v - bf_f(hi));
}

// ------- waux: fp32 aux rows WfA[d][3][NO]: ch0=x (W row0), ch1=ax64 (W row129), ch2=bias -------
__global__ __launch_bounds__(256) void waux_kernel(
    const float* __restrict__ W, const float* __restrict__ bias,
    int NO, float* __restrict__ WfA)
{
  int i = blockIdx.x*256 + threadIdx.x;
  int total = DD*3*NO;
  if (i >= total) return;
  int o = i % NO; int r = i / NO;
  int ch = r % 3; int d = r / 3;
  float v;
  if (ch == 0)      v = W[(size_t)(d*130 + 0)*NO + o];
  else if (ch == 1) v = W[(size_t)(d*130 + 129)*NO + o];
  else              v = bias[d*NO + o];
  WfA[i] = v;
}

// =========================================================================
// Fused attention + GEMM kernels. grid (NT, BB), 256 threads, 3 blocks/CU.
// GEMM: barrier-free register-B (each wave loads its private B-frags from L2),
// KF=4 MFMA + fp32 rank-1 (x, ax64) + bias per d. LDS U = 40448 B:
//   attn phase:  XT@0 (16384) | PT@16384 (18432) | nv2s@34816 (5120) | xcolb@39936 (512)
//   XA phase:    XA@0 (36864) [4kf][64m][72sh]
//   epilogue:    CT@0 [64][67] f32 (+PS)
// =========================================================================

// ---------------- attn_gate: attn(h) -> gate GEMM (NO=128, 2 co-halves) ----------------
__global__ __launch_bounds__(256,3) void attn_gate(
    const float* __restrict__ nv1T, const float* __restrict__ nv2T,
    const unsigned short* __restrict__ Xs,   // XsH
    const float* __restrict__ h,             // h state (xcol row63, r63, z*h epilogue)
    const unsigned short* __restrict__ Wf,   // [10][2][4][4][128][8]
    const float* __restrict__ WfA,           // [10][3][128]
    float* __restrict__ rbuf,
    unsigned short* __restrict__ XsZ, float* __restrict__ zh63)
{
  __shared__ float nv1s[DD][64];
  __shared__ float linv[64];
  __shared__ float xrow[64];
  __shared__ float ax64r[64];
  __shared__ alignas(16) unsigned char U[40448];
  unsigned short* XT = (unsigned short*)U;
  unsigned short* PT = (unsigned short*)(U + 16384);
  float* nv2s = (float*)(U + 34816);
  float* xcolb = (float*)(U + 39936);
  int b, rt;
  swz_block(b, rt);
  int r0 = rt*64;
  int tid = threadIdx.x;
  int rg = tid >> 4, cg = tid & 15;
  int base = b*NN;
  int lane = tid & 63, lm = lane & 15, quad = lane >> 4;
  int w = tid >> 6, mp = w >> 1, np = w & 1;
  const unsigned short* XsB = Xs + (size_t)b*NT*8192;

  for (int idx = tid; idx < DD*64; idx += 256) {
    int d = idx >> 6, r = idx & 63;
    nv1s[d][r] = (r0 + r < NN) ? nv1T[d*BNP + base + r0 + r] : 0.f;
  }

  int4 xt[4];
  float nvr[3]; float xcr;
  {
    const int4* s0 = (const int4*)XsB;
#pragma unroll
    for (int i = 0; i < 4; ++i) xt[i] = s0[w*64 + lane + i*256];
#pragma unroll
    for (int i = 0; i < 3; ++i) {
      int idx = tid + i*256; float v = 0.f;
      if (idx < DD*64) { int d = idx>>6, m = idx&63; v = (m < NN) ? nv2T[d*BNP + base + m] : 0.f; }
      nvr[i] = v;
    }
    xcr = (tid < 64 && tid < NN) ? h[(size_t)63*BNP + base + tid] : 0.f;
#pragma unroll
    for (int i = 0; i < 4; ++i)
      *(int4*)((char*)XT + w*1024 + lane*16 + i*4096) = xt[i];
#pragma unroll
    for (int i = 0; i < 3; ++i) {
      int idx = tid + i*256;
      if (idx < DD*64) nv2s[idx] = nvr[i];
    }
    if (tid < 64) xcolb[tid] = xcr;
  }
  __syncthreads();

  f32x4 accv[2][2] = {};
  float acclp[4] = {}, acc5p[4] = {};

  for (int tI = 0; tI < NT; ++tI) {
    int cur = tI & 1, nxt = cur ^ 1;
    int m0 = tI*64, m0n = m0 + 64;
    bool hasn = tI < NT-1;
    if (hasn) {
      const int4* src = (const int4*)(XsB + (size_t)(tI+1)*8192);
#pragma unroll
      for (int i = 0; i < 4; ++i) xt[i] = src[w*64 + lane + i*256];
#pragma unroll
      for (int i = 0; i < 3; ++i) {
        int idx = tid + i*256; float v = 0.f;
        if (idx < DD*64) { int d = idx>>6, m = idx&63; v = (m0n + m < NN) ? nv2T[d*BNP + base + m0n + m] : 0.f; }
        nvr[i] = v;
      }
      xcr = (tid < 64 && m0n + tid < NN) ? h[(size_t)63*BNP + base + m0n + tid] : 0.f;
    }
    float s[4][4] = {};
#pragma unroll
    for (int d = 0; d < DD; ++d) {
      float4 a4 = *(const float4*)&nv1s[d][rg*4];
      float4 c4 = *(const float4*)&nv2s[cur*(DD*64) + d*64 + cg*4];
      const float* ap = (const float*)&a4;
      const float* cp = (const float*)&c4;
#pragma unroll
      for (int j = 0; j < 4; ++j)
#pragma unroll
        for (int jj = 0; jj < 4; ++jj)
          s[j][jj] += ap[j]*cp[jj];
    }
    int mvlim = NN - m0;
    float ev[4][4];
#pragma unroll
    for (int jj = 0; jj < 4; ++jj) {
      int m = cg*4 + jj;
      float xm = xcolb[cur*64 + m];
      bool okm = m < mvlim;
#pragma unroll
      for (int j = 0; j < 4; ++j) {
        float e = okm ? __expf(fmaxf(s[j][jj], 0.f)) : 0.f;
        ev[j][jj] = e;
        acclp[j] += e;
        acc5p[j] = fmaf(e, xm, acc5p[j]);
      }
    }
    {
      unsigned int* P1 = (unsigned int*)PT;
      unsigned int* P2 = (unsigned int*)(PT + 64*72);
#pragma unroll
      for (int j = 0; j < 4; ++j) {
        int r = rg*4 + j;
        unsigned int h0 = bf_hi(ev[j][0]), h1 = bf_hi(ev[j][1]), h2 = bf_hi(ev[j][2]), h3 = bf_hi(ev[j][3]);
        unsigned int l0 = bf_hi(ev[j][0]-bf_f(h0)), l1 = bf_hi(ev[j][1]-bf_f(h1));
        unsigned int l2 = bf_hi(ev[j][2]-bf_f(h2)), l3 = bf_hi(ev[j][3]-bf_f(h3));
        int dw = r*36 + cg*2;
        P1[dw] = h0 | (h1 << 16); P1[dw+1] = h2 | (h3 << 16);
        P2[dw] = l0 | (l1 << 16); P2[dw+1] = l2 | (l3 << 16);
      }
    }
    __syncthreads();
    {
      short8 Aa[2][2], Ab[2][2], Ba[2][2], Bb[2][2];
#pragma unroll
      for (int mt = 0; mt < 2; ++mt) {
        int r = mp*32 + mt*16 + lm;
#pragma unroll
        for (int kf = 0; kf < 2; ++kf) {
          Aa[mt][kf] = *(const short8*)&PT[r*72 + quad*8 + kf*32];
          Ab[mt][kf] = *(const short8*)&PT[64*72 + r*72 + quad*8 + kf*32];
        }
      }
#pragma unroll
      for (int ntl = 0; ntl < 2; ++ntl) {
        int c = np*32 + ntl*16 + lm;
        int swz = (c & 7) << 4;
        int cb0 = c*128 + quad*16;
#pragma unroll
        for (int kf = 0; kf < 2; ++kf) {
          int a = (cb0 + kf*64) ^ swz;
          Ba[ntl][kf] = *(const short8*)((const char*)XT + a);
          Bb[ntl][kf] = *(const short8*)((const char*)XT + a + 8192);
        }
      }
#pragma unroll
      for (int kf = 0; kf < 2; ++kf)
#pragma unroll
        for (int mt = 0; mt < 2; ++mt)
#pragma unroll
          for (int ntl = 0; ntl < 2; ++ntl) {
            accv[mt][ntl] = __builtin_amdgcn_mfma_f32_16x16x32_bf16(Aa[mt][kf], Ba[ntl][kf], accv[mt][ntl], 0,0,0);
            accv[mt][ntl] = __builtin_amdgcn_mfma_f32_16x16x32_bf16(Aa[mt][kf], Bb[ntl][kf], accv[mt][ntl], 0,0,0);
            accv[mt][ntl] = __builtin_amdgcn_mfma_f32_16x16x32_bf16(Ab[mt][kf], Ba[ntl][kf], accv[mt][ntl], 0,0,0);
          }
    }
    if (hasn) {
#pragma unroll
      for (int i = 0; i < 3; ++i) {
        int idx = tid + i*256;
        if (idx < DD*64) nv2s[nxt*(DD*64) + idx] = nvr[i];
      }
      if (tid < 64) xcolb[nxt*64 + tid] = xcr;
    }
    __syncthreads();
    if (hasn) {
#pragma unroll
      for (int i = 0; i < 4; ++i)
        *(int4*)((char*)XT + w*1024 + lane*16 + i*4096) = xt[i];
    }
  }
  // ---- A-source (h channels 0..63) from own Xs chunk + row63 fp32 ----
  int mrow_x = tid >> 2, ksub = tid & 3;
  int gmx = base + r0 + mrow_x;
  const unsigned short* chk_in = Xs + (size_t)(b*NT + rt)*8192;
  int mm2x = mrow_x*2;
  unsigned int pjh[8], pjl[8];
  {
    float r63v = h[(size_t)63*BNP + gmx];
    unsigned int h63 = bf_hi(r63v);
    unsigned int l63 = bf_hi(r63v - bf_f(h63));
#pragma unroll
    for (int i = 0; i < 8; ++i) {
      int kk = ksub*2 + 8*i;   // 0..62 even
      int c0 = kk + 1;
      int idx0 = (c0*128 + (mm2x ^ ((c0 & 7) << 4))) >> 1;
      unsigned int h0 = chk_in[idx0], l0 = chk_in[idx0 + 4096];
      unsigned int h1, l1;
      int k1 = kk + 1;
      if (k1 == 63) { h1 = h63; l1 = l63; }
      else { int c1 = k1 + 1; int idx1 = (c1*128 + (mm2x ^ ((c1 & 7) << 4))) >> 1; h1 = chk_in[idx1]; l1 = chk_in[idx1 + 4096]; }
      pjh[i] = h0 | (h1 << 16);
      pjl[i] = l0 | (l1 << 16);
    }
  }
#pragma unroll
  for (int off = 1; off <= 8; off <<= 1)
#pragma unroll
    for (int j = 0; j < 4; ++j) {
      acclp[j] += __shfl_xor(acclp[j], off, 64);
      acc5p[j] += __shfl_xor(acc5p[j], off, 64);
    }
  __syncthreads();   // attn LDS dead
  unsigned short* XA = (unsigned short*)U;
  if (cg == 0) {
#pragma unroll
    for (int j = 0; j < 4; ++j) {
      float li = 1.f / acclp[j];
      int r = rg*4 + j;
      linv[r] = li;
      ax64r[r] = acc5p[j]*li;   // fp32 rank-1 channel (tail rows produce discarded values)
    }
  }
  if (tid < 64) xrow[tid] = bf_f(chk_in[tid]) + bf_f(chk_in[4096 + tid]);
  __syncthreads();
  // ax scatter: kk'=64+c from accv*li
#pragma unroll
  for (int mt = 0; mt < 2; ++mt) {
    int rbase = mp*32 + mt*16 + quad*4;
    float4 lv = *(const float4*)&linv[rbase];
    const float* lvp = (const float*)&lv;
#pragma unroll
    for (int ntl = 0; ntl < 2; ++ntl) {
      int c = np*32 + ntl*16 + lm;
      int kk = 64 + c;
      int kf = kk >> 5, kkl = kk & 31;
#pragma unroll
      for (int r4 = 0; r4 < 4; ++r4) {
        float v = accv[mt][ntl][r4] * lvp[r4];
        unsigned int hi = bf_hi(v);
        int p = (kf*64 + rbase + r4)*72 + kkl;
        XA[p] = (unsigned short)hi;
        XA[p + 32] = (unsigned short)bf_hi(v - bf_f(hi));
      }
    }
  }
  // h fill (kk' pairs 0..63)
  {
    unsigned int* X1 = (unsigned int*)U;
#pragma unroll
    for (int i = 0; i < 8; ++i) {
      int kk = ksub*2 + 8*i;
      int kf = kk >> 5, kkl = kk & 31;
      int dw = (kf*64 + mrow_x)*36 + (kkl >> 1);
      X1[dw] = pjh[i];
      X1[dw + 16] = pjl[i];
    }
  }
  __syncthreads();
  // A-frags + per-lane row values to regs
  short8 A1[2][KF], A2[2][KF];
#pragma unroll
  for (int mt = 0; mt < 2; ++mt) {
    int mrow = mp*32 + mt*16 + lm;
#pragma unroll
    for (int kf = 0; kf < KF; ++kf) {
      A1[mt][kf] = *(const short8*)&XA[(kf*64 + mrow)*72 + quad*8];
      A2[mt][kf] = *(const short8*)&XA[(kf*64 + mrow)*72 + 32 + quad*8];
    }
  }
  float xvr[2][4], avr[2][4];
#pragma unroll
  for (int mt = 0; mt < 2; ++mt) {
    float4 xq = *(const float4*)&xrow[mp*32 + mt*16 + quad*4];
    float4 aq = *(const float4*)&ax64r[mp*32 + mt*16 + quad*4];
    xvr[mt][0]=xq.x; xvr[mt][1]=xq.y; xvr[mt][2]=xq.z; xvr[mt][3]=xq.w;
    avr[mt][0]=aq.x; avr[mt][1]=aq.y; avr[mt][2]=aq.z; avr[mt][3]=aq.w;
  }
  const int colb = np*32 + lm;
#pragma unroll 1
  for (int co = 0; co < 2; ++co) {
    int co0 = co*64;
    int cA0 = co0 + colb, cA1 = cA0 + 16;
    f32x4 accO[2][2] = {};
#pragma unroll 1
    for (int d = 0; d < DD; ++d) {
      f32x4 td[2][2] = {};
      float wx0 = WfA[(d*3+0)*128 + cA0], wx1 = WfA[(d*3+0)*128 + cA1];
      float wa0 = WfA[(d*3+1)*128 + cA0], wa1 = WfA[(d*3+1)*128 + cA1];
      float wb0 = WfA[(d*3+2)*128 + cA0], wb1 = WfA[(d*3+2)*128 + cA1];
#pragma unroll
      for (int kf = 0; kf < KF; ++kf) {
        size_t obh = (((size_t)(d*2+0)*4 + kf)*4 + quad)*128;
        size_t obl = (((size_t)(d*2+1)*4 + kf)*4 + quad)*128;
        short8 Bh0 = *(const short8*)(Wf + (obh + cA0)*8);
        short8 Bh1 = *(const short8*)(Wf + (obh + cA1)*8);
        short8 Bl0 = *(const short8*)(Wf + (obl + cA0)*8);
        short8 Bl1 = *(const short8*)(Wf + (obl + cA1)*8);
        td[0][0] = __builtin_amdgcn_mfma_f32_16x16x32_bf16(A1[0][kf], Bh0, td[0][0], 0,0,0);
        td[0][0] = __builtin_amdgcn_mfma_f32_16x16x32_bf16(A2[0][kf], Bh0, td[0][0], 0,0,0);
        td[1][0] = __builtin_amdgcn_mfma_f32_16x16x32_bf16(A1[1][kf], Bh0, td[1][0], 0,0,0);
        td[1][0] = __builtin_amdgcn_mfma_f32_16x16x32_bf16(A2[1][kf], Bh0, td[1][0], 0,0,0);
        td[0][0] = __builtin_amdgcn_mfma_f32_16x16x32_bf16(A1[0][kf], Bl0, td[0][0], 0,0,0);
        td[1][0] = __builtin_amdgcn_mfma_f32_16x16x32_bf16(A1[1][kf], Bl0, td[1][0], 0,0,0);
        td[0][1] = __builtin_amdgcn_mfma_f32_16x16x32_bf16(A1[0][kf], Bh1, td[0][1], 0,0,0);
        td[0][1] = __builtin_amdgcn_mfma_f32_16x16x32_bf16(A2[0][kf], Bh1, td[0][1], 0,0,0);
        td[1][1] = __builtin_amdgcn_mfma_f32_16x16x32_bf16(A1[1][kf], Bh1, td[1][1], 0,0,0);
        td[1][1] = __builtin_amdgcn_mfma_f32_16x16x32_bf16(A2[1][kf], Bh1, td[1][1], 0,0,0);
        td[0][1] = __builtin_amdgcn_mfma_f32_16x16x32_bf16(A1[0][kf], Bl1, td[0][1], 0,0,0);
        td[1][1] = __builtin_amdgcn_mfma_f32_16x16x32_bf16(A1[1][kf], Bl1, td[1][1], 0,0,0);
      }
#pragma unroll
      for (int mt = 0; mt < 2; ++mt) {
        float4 nv4 = *(const float4*)&nv1s[d][mp*32 + mt*16 + quad*4];
        const float* nvp = (const float*)&nv4;
#pragma unroll
        for (int r = 0; r < 4; ++r) {
          float t0 = td[mt][0][r] + wb0 + xvr[mt][r]*wx0 + avr[mt][r]*wa0;
          float t1 = td[mt][1][r] + wb1 + xvr[mt][r]*wx1 + avr[mt][r]*wa1;
          accO[mt][0][r] += nvp[r] * t0;
          accO[mt][1][r] += nvp[r] * t1;
        }
      }
    }
    float* CT = (float*)U;
    __syncthreads();
#pragma unroll
    for (int mt = 0; mt < 2; ++mt)
#pragma unroll
      for (int ntl = 0; ntl < 2; ++ntl)
#pragma unroll
        for (int r = 0; r < 4; ++r)
          CT[(mp*32 + mt*16 + quad*4 + r)*67 + np*32 + ntl*16 + lm] = accO[mt][ntl][r];
    __syncthreads();
    {
      int mm = tid & 63, og = tid >> 6;
      int n = r0 + mm;
      int gm = base + n;
      bool okn = n < NN;
      if (co == 0) {
        unsigned short* chk = XsZ + ((size_t)(b*NT + rt))*8192;
        int mm2 = mm*2;
        for (int j = 0; j < 16; ++j) {
          int o = og*16 + j;
          float z = sigmf(CT[mm*67 + o]);
          float zhv = z * h[(size_t)o*BNP + gm];
          if (okn) {
            if (o < 63) xs_store(chk, o + 1, mm2, zhv);
            else zh63[gm] = zhv;
          }
        }
      } else {
        for (int j = 0; j < 16; ++j) {
          int o = og*16 + j;
          if (okn) rbuf[(size_t)o*BNP + gm] = sigmf(CT[mm*67 + o]);
        }
      }
    }
    __syncthreads();  // CT reads done before next co reuses U
  }
}

// ---------------- attn_upd: attn(zh) -> upd GEMM (NO=64); dec: fused proj ----------------
// xnmode: 0=none, 1=write src_vals[xnt] as next x column, 2=write zeros, 3=write computed go (dec)
__global__ __launch_bounds__(256,3) void attn_upd(
    const float* __restrict__ nv1T, const float* __restrict__ nv2T,
    const unsigned short* __restrict__ Xs,   // XsZ (B-stream + A-source chunk)
    const float* __restrict__ zh63,          // zh row 63 fp32 (xcol + A channel 63)
    float* __restrict__ hstate,              // h (read/modify/write)
    const unsigned short* __restrict__ Wf,   // [10][2][4][4][64][8]
    const float* __restrict__ WfA,           // [10][3][64]
    const float* __restrict__ rbuf,
    int dec, const float* __restrict__ pW, const float* __restrict__ pb,
    float* __restrict__ go, float* __restrict__ dout,
    unsigned short* __restrict__ XsH, int t,
    const float* __restrict__ xsrc, int xnmode, int xnt,
    unsigned short* __restrict__ XsZm)
{
  __shared__ float nv1s[DD][64];
  __shared__ float linv[64];
  __shared__ float xrow[64];
  __shared__ float ax64r[64];
  __shared__ alignas(16) unsigned char U[40448];
  unsigned short* XT = (unsigned short*)U;
  unsigned short* PT = (unsigned short*)(U + 16384);
  float* nv2s = (float*)(U + 34816);
  float* xcolb = (float*)(U + 39936);
  int b, rt;
  swz_block(b, rt);
  int r0 = rt*64;
  int tid = threadIdx.x;
  int rg = tid >> 4, cg = tid & 15;
  int base = b*NN;
  int lane = tid & 63, lm = lane & 15, quad = lane >> 4;
  int w = tid >> 6, mp = w >> 1, np = w & 1;
  const unsigned short* XsB = Xs + (size_t)b*NT*8192;

  for (int idx = tid; idx < DD*64; idx += 256) {
    int d = idx >> 6, r = idx & 63;
    nv1s[d][r] = (r0 + r < NN) ? nv1T[d*BNP + base + r0 + r] : 0.f;
  }

  int4 xt[4];
  float nvr[3]; float xcr;
  {
    const int4* s0 = (const int4*)XsB;
#pragma unroll
    for (int i = 0; i < 4; ++i) xt[i] = s0[w*64 + lane + i*256];
#pragma unroll
    for (int i = 0; i < 3; ++i) {
      int idx = tid + i*256; float v = 0.f;
      if (idx < DD*64) { int d = idx>>6, m = idx&63; v = (m < NN) ? nv2T[d*BNP + base + m] : 0.f; }
      nvr[i] = v;
    }
    xcr = (tid < 64 && tid < NN) ? zh63[base + tid] : 0.f;
#pragma unroll
    for (int i = 0; i < 4; ++i)
      *(int4*)((char*)XT + w*1024 + lane*16 + i*4096) = xt[i];
#pragma unroll
    for (int i = 0; i < 3; ++i) {
      int idx = tid + i*256;
      if (idx < DD*64) nv2s[idx] = nvr[i];
    }
    if (tid < 64) xcolb[tid] = xcr;
  }
  __syncthreads();

  f32x4 accv[2][2] = {};
  float acclp[4] = {}, acc5p[4] = {};

  for (int tI = 0; tI < NT; ++tI) {
    int cur = tI & 1, nxt = cur ^ 1;
    int m0 = tI*64, m0n = m0 + 64;
    bool hasn = tI < NT-1;
    if (hasn) {
      const int4* src = (const int4*)(XsB + (size_t)(tI+1)*8192);
#pragma unroll
      for (int i = 0; i < 4; ++i) xt[i] = src[w*64 + lane + i*256];
#pragma unroll
      for (int i = 0; i < 3; ++i) {
        int idx = tid + i*256; float v = 0.f;
        if (idx < DD*64) { int d = idx>>6, m = idx&63; v = (m0n + m < NN) ? nv2T[d*BNP + base + m0n + m] : 0.f; }
        nvr[i] = v;
      }
      xcr = (tid < 64 && m0n + tid < NN) ? zh63[base + m0n + tid] : 0.f;
    }
    float s[4][4] = {};
#pragma unroll
    for (int d = 0; d < DD; ++d) {
      float4 a4 = *(const float4*)&nv1s[d][rg*4];
      float4 c4 = *(const float4*)&nv2s[cur*(DD*64) + d*64 + cg*4];
      const float* ap = (const float*)&a4;
      const float* cp = (const float*)&c4;
#pragma unroll
      for (int j = 0; j < 4; ++j)
#pragma unroll
        for (int jj = 0; jj < 4; ++jj)
          s[j][jj] += ap[j]*cp[jj];
    }
    int mvlim = NN - m0;
    float ev[4][4];
#pragma unroll
    for (int jj = 0; jj < 4; ++jj) {
      int m = cg*4 + jj;
      float xm = xcolb[cur*64 + m];
      bool okm = m < mvlim;
#pragma unroll
      for (int j = 0; j < 4; ++j) {
        float e = okm ? __expf(fmaxf(s[j][jj], 0.f)) : 0.f;
        ev[j][jj] = e;
        acclp[j] += e;
        acc5p[j] = fmaf(e, xm, acc5p[j]);
      }
    }
    {
      unsigned int* P1 = (unsigned int*)PT;
      unsigned int* P2 = (unsigned int*)(PT + 64*72);
#pragma unroll
      for (int j = 0; j < 4; ++j) {
        int r = rg*4 + j;
        unsigned int h0 = bf_hi(ev[j][0]), h1 = bf_hi(ev[j][1]), h2 = bf_hi(ev[j][2]), h3 = bf_hi(ev[j][3]);
        unsigned int l0 = bf_hi(ev[j][0]-bf_f(h0)), l1 = bf_hi(ev[j][1]-bf_f(h1));
        unsigned int l2 = bf_hi(ev[j][2]-bf_f(h2)), l3 = bf_hi(ev[j][3]-bf_f(h3));
        int dw = r*36 + cg*2;
        P1[dw] = h0 | (h1 << 16); P1[dw+1] = h2 | (h3 << 16);
        P2[dw] = l0 | (l1 << 16); P2[dw+1] = l2 | (l3 << 16);
      }
    }
    __syncthreads();
    {
      short8 Aa[2][2], Ab[2][2], Ba[2][2], Bb[2][2];
#pragma unroll
      for (int mt = 0; mt < 2; ++mt) {
        int r = mp*32 + mt*16 + lm;
#pragma unroll
        for (int kf = 0; kf < 2; ++kf) {
          Aa[mt][kf] = *(const short8*)&PT[r*72 + quad*8 + kf*32];
          Ab[mt][kf] = *(const short8*)&PT[64*72 + r*72 + quad*8 + kf*32];
        }
      }
#pragma unroll
      for (int ntl = 0; ntl < 2; ++ntl) {
        int c = np*32 + ntl*16 + lm;
        int swz = (c & 7) << 4;
        int cb0 = c*128 + quad*16;
#pragma unroll
        for (int kf = 0; kf < 2; ++kf) {
          int a = (cb0 + kf*64) ^ swz;
          Ba[ntl][kf] = *(const short8*)((const char*)XT + a);
          Bb[ntl][kf] = *(const short8*)((const char*)XT + a + 8192);
        }
      }
#pragma unroll
      for (int kf = 0; kf < 2; ++kf)
#pragma unroll
        for (int mt = 0; mt < 2; ++mt)
#pragma unroll
          for (int ntl = 0; ntl < 2; ++ntl) {
            accv[mt][ntl] = __builtin_amdgcn_mfma_f32_16x16x32_bf16(Aa[mt][kf], Ba[ntl][kf], accv[mt][ntl], 0,0,0);
            accv[mt][ntl] = __builtin_amdgcn_mfma_f32_16x16x32_bf16(Aa[mt][kf], Bb[ntl][kf], accv[mt][ntl], 0,0,0);
            accv[mt][ntl] = __builtin_amdgcn_mfma_f32_16x16x32_bf16(Ab[mt][kf], Ba[ntl][kf], accv[mt][ntl], 0,0,0);
          }
    }
    if (hasn) {
#pragma unroll
      for (int i = 0; i < 3; ++i) {
        int idx = tid + i*256;
        if (idx < DD*64) nv2s[nxt*(DD*64) + idx] = nvr[i];
      }
      if (tid < 64) xcolb[nxt*64 + tid] = xcr;
    }
    __syncthreads();
    if (hasn) {
#pragma unroll
      for (int i = 0; i < 4; ++i)
        *(int4*)((char*)XT + w*1024 + lane*16 + i*4096) = xt[i];
    }
  }
  int mrow_x = tid >> 2, ksub = tid & 3;
  int gmx = base + r0 + mrow_x;
  const unsigned short* chk_in = Xs + (size_t)(b*NT + rt)*8192;
  int mm2x = mrow_x*2;
  unsigned int pjh[8], pjl[8];
  {
    float r63v = zh63[gmx];
    unsigned int h63 = bf_hi(r63v);
    unsigned int l63 = bf_hi(r63v - bf_f(h63));
#pragma unroll
    for (int i = 0; i < 8; ++i) {
      int kk = ksub*2 + 8*i;
      int c0 = kk + 1;
      int idx0 = (c0*128 + (mm2x ^ ((c0 & 7) << 4))) >> 1;
      unsigned int h0 = chk_in[idx0], l0 = chk_in[idx0 + 4096];
      unsigned int h1, l1;
      int k1 = kk + 1;
      if (k1 == 63) { h1 = h63; l1 = l63; }
      else { int c1 = k1 + 1; int idx1 = (c1*128 + (mm2x ^ ((c1 & 7) << 4))) >> 1; h1 = chk_in[idx1]; l1 = chk_in[idx1 + 4096]; }
      pjh[i] = h0 | (h1 << 16);
      pjl[i] = l0 | (l1 << 16);
    }
  }
#pragma unroll
  for (int off = 1; off <= 8; off <<= 1)
#pragma unroll
    for (int j = 0; j < 4; ++j) {
      acclp[j] += __shfl_xor(acclp[j], off, 64);
      acc5p[j] += __shfl_xor(acc5p[j], off, 64);
    }
  __syncthreads();
  unsigned short* XA = (unsigned short*)U;
  if (cg == 0) {
#pragma unroll
    for (int j = 0; j < 4; ++j) {
      float li = 1.f / acclp[j];
      int r = rg*4 + j;
      linv[r] = li;
      ax64r[r] = acc5p[j]*li;
    }
  }
  if (tid < 64) xrow[tid] = bf_f(chk_in[tid]) + bf_f(chk_in[4096 + tid]);
  __syncthreads();
#pragma unroll
  for (int mt = 0; mt < 2; ++mt) {
    int rbase = mp*32 + mt*16 + quad*4;
    float4 lv = *(const float4*)&linv[rbase];
    const float* lvp = (const float*)&lv;
#pragma unroll
    for (int ntl = 0; ntl < 2; ++ntl) {
      int c = np*32 + ntl*16 + lm;
      int kk = 64 + c;
      int kf = kk >> 5, kkl = kk & 31;
#pragma unroll
      for (int r4 = 0; r4 < 4; ++r4) {
        float v = accv[mt][ntl][r4] * lvp[r4];
        unsigned int hi = bf_hi(v);
        int p = (kf*64 + rbase + r4)*72 + kkl;
        XA[p] = (unsigned short)hi;
        XA[p + 32] = (unsigned short)bf_hi(v - bf_f(hi));
      }
    }
  }
  {
    unsigned int* X1 = (unsigned int*)U;
#pragma unroll
    for (int i = 0; i < 8; ++i) {
      int kk = ksub*2 + 8*i;
      int kf = kk >> 5, kkl = kk & 31;
      int dw = (kf*64 + mrow_x)*36 + (kkl >> 1);
      X1[dw] = pjh[i];
      X1[dw + 16] = pjl[i];
    }
  }
  __syncthreads();
  short8 A1[2][KF], A2[2][KF];
#pragma unroll
  for (int mt = 0; mt < 2; ++mt) {
    int mrow = mp*32 + mt*16 + lm;
#pragma unroll
    for (int kf = 0; kf < KF; ++kf) {
      A1[mt][kf] = *(const short8*)&XA[(kf*64 + mrow)*72 + quad*8];
      A2[mt][kf] = *(const short8*)&XA[(kf*64 + mrow)*72 + 32 + quad*8];
    }
  }
  float xvr[2][4], avr[2][4];
#pragma unroll
  for (int mt = 0; mt < 2; ++mt) {
    float4 xq = *(const float4*)&xrow[mp*32 + mt*16 + quad*4];
    float4 aq = *(const float4*)&ax64r[mp*32 + mt*16 + quad*4];
    xvr[mt][0]=xq.x; xvr[mt][1]=xq.y; xvr[mt][2]=xq.z; xvr[mt][3]=xq.w;
    avr[mt][0]=aq.x; avr[mt][1]=aq.y; avr[mt][2]=aq.z; avr[mt][3]=aq.w;
  }
  const int colb = np*32 + lm;
  const int cA0 = colb, cA1 = colb + 16;
  f32x4 accO[2][2] = {};
#pragma unroll 1
  for (int d = 0; d < DD; ++d) {
    f32x4 td[2][2] = {};
    float wx0 = WfA[(d*3+0)*64 + cA0], wx1 = WfA[(d*3+0)*64 + cA1];
    float wa0 = WfA[(d*3+1)*64 + cA0], wa1 = WfA[(d*3+1)*64 + cA1];
    float wb0 = WfA[(d*3+2)*64 + cA0], wb1 = WfA[(d*3+2)*64 + cA1];
#pragma unroll
    for (int kf = 0; kf < KF; ++kf) {
      size_t obh = (((size_t)(d*2+0)*4 + kf)*4 + quad)*64;
      size_t obl = (((size_t)(d*2+1)*4 + kf)*4 + quad)*64;
      short8 Bh0 = *(const short8*)(Wf + (obh + cA0)*8);
      short8 Bh1 = *(const short8*)(Wf + (obh + cA1)*8);
      short8 Bl0 = *(const short8*)(Wf + (obl + cA0)*8);
      short8 Bl1 = *(const short8*)(Wf + (obl + cA1)*8);
      td[0][0] = __builtin_amdgcn_mfma_f32_16x16x32_bf16(A1[0][kf], Bh0, td[0][0], 0,0,0);
      td[0][0] = __builtin_amdgcn_mfma_f32_16x16x32_bf16(A2[0][kf], Bh0, td[0][0], 0,0,0);
      td[1][0] = __builtin_amdgcn_mfma_f32_16x16x32_bf16(A1[1][kf], Bh0, td[1][0], 0,0,0);
      td[1][0] = __builtin_amdgcn_mfma_f32_16x16x32_bf16(A2[1][kf], Bh0, td[1][0], 0,0,0);
      td[0][0] = __builtin_amdgcn_mfma_f32_16x16x32_bf16(A1[0][kf], Bl0, td[0][0], 0,0,0);
      td[1][0] = __builtin_amdgcn_mfma_f32_16x16x32_bf16(A1[1][kf], Bl0, td[1][0], 0,0,0);
      td[0][1] = __builtin_amdgcn_mfma_f32_16x16x32_bf16(A1[0][kf], Bh1, td[0][1], 0,0,0);
      td[0][1] = __builtin_amdgcn_mfma_f32_16x16x32_bf16(A2[0][kf], Bh1, td[0][1], 0,0,0);
      td[1][1] = __builtin_amdgcn_mfma_f32_16x16x32_bf16(A1[1][kf], Bh1, td[1][1], 0,0,0);
      td[1][1] = __builtin_amdgcn_mfma_f32_16x16x32_bf16(A2[1][kf], Bh1, td[1][1], 0,0,0);
      td[0][1] = __builtin_amdgcn_mfma_f32_16x16x32_bf16(A1[0][kf], Bl1, td[0][1], 0,0,0);
      td[1][1] = __builtin_amdgcn_mfma_f32_16x16x32_bf16(A1[1][kf], Bl1, td[1][1], 0,0,0);
    }
#pragma unroll
    for (int mt = 0; mt < 2; ++mt) {
      float4 nv4 = *(const float4*)&nv1s[d][mp*32 + mt*16 + quad*4];
      const float* nvp = (const float*)&nv4;
#pragma unroll
      for (int r = 0; r < 4; ++r) {
        float t0 = td[mt][0][r] + wb0 + xvr[mt][r]*wx0 + avr[mt][r]*wa0;
        float t1 = td[mt][1][r] + wb1 + xvr[mt][r]*wx1 + avr[mt][r]*wa1;
        accO[mt][0][r] += nvp[r] * t0;
        accO[mt][1][r] += nvp[r] * t1;
      }
    }
  }
  float* CT = (float*)U;
  __syncthreads();
#pragma unroll
  for (int mt = 0; mt < 2; ++mt)
#pragma unroll
    for (int ntl = 0; ntl < 2; ++ntl)
#pragma unroll
      for (int r = 0; r < 4; ++r)
        CT[(mp*32 + mt*16 + quad*4 + r)*67 + np*32 + ntl*16 + lm] = accO[mt][ntl][r];
  __syncthreads();
  {
    int mm = tid & 63, og = tid >> 6;
    int n = r0 + mm;
    int gm = base + n;
    bool okn = n < NN;
    unsigned short* chk = XsH + ((size_t)(b*NT + rt))*8192;
    int mm2 = mm*2;
    float pp = 0.f;
    float sval = 0.f;
    for (int j = 0; j < 16; ++j) {
      int o = og*16 + j;
      float hc = tanhf(CT[mm*67 + o]);
      float r = rbuf[(size_t)o*BNP + gm];
      float hv = hstate[(size_t)o*BNP + gm];
      float hn = r*hv + (1.f - r)*hc;
      if (okn) {
        hstate[(size_t)o*BNP + gm] = hn;
        if (o < 63) xs_store(chk, o + 1, mm2, hn);
      }
      if (dec) pp = fmaf(hn, pW[o], pp);
    }
    if (dec) {
      float* PS = CT + 64*67;
      __syncthreads();
      PS[mm*4 + og] = pp;
      __syncthreads();
      if (tid < 64) {
        int n2 = r0 + tid;
        if (n2 < NN) {
          float s = pb[0] + PS[tid*4] + PS[tid*4+1] + PS[tid*4+2] + PS[tid*4+3];
          go[base + n2] = s;
          dout[(b*HORZ + t)*NN + n2] = s;
          sval = s;
        }
      }
    }
    // ---- next-step x-column handoff ----
    if (xnmode) {
      if (tid < 64) {
        int n2 = r0 + tid;
        if (n2 < NN) {
          float xn;
          if (xnmode == 1)      xn = xsrc[(b*TSRC + xnt)*NN + n2];
          else if (xnmode == 2) xn = 0.f;
          else                  xn = sval;
          unsigned int hix = bf_hi(xn);
          unsigned short lox = (unsigned short)bf_hi(xn - bf_f(hix));
          unsigned short* cH = XsH + ((size_t)(b*NT + rt))*8192;
          unsigned short* cZ = XsZm + ((size_t)(b*NT + rt))*8192;
          cH[tid] = (unsigned short)hix; cH[4096 + tid] = lox;
          cZ[tid] = (unsigned short)hix; cZ[4096 + tid] = lox;
        }
      }
    }
  }
}

extern "C" void kernel_launch(void* const* d_in, const int* in_sizes, int n_in,
                              void* d_out, int out_size, void* d_ws, size_t ws_size,
                              hipStream_t stream) {
  (void)in_sizes; (void)n_in; (void)out_size; (void)ws_size;
  const float* src_vals = (const float*)d_in[0];
  const float* node_emb = (const float*)d_in[1];
  const float* tid1 = (const float*)d_in[2];
  const float* tid2 = (const float*)d_in[3];
  const float* diw1 = (const float*)d_in[4];
  const float* diw2 = (const float*)d_in[5];
  const float* egW = (const float*)d_in[6];
  const float* egb = (const float*)d_in[7];
  const float* euW = (const float*)d_in[8];
  const float* eub = (const float*)d_in[9];
  const float* dgW = (const float*)d_in[10];
  const float* dgb = (const float*)d_in[11];
  const float* duW = (const float*)d_in[12];
  const float* dub = (const float*)d_in[13];
  const float* pW  = (const float*)d_in[14];
  const float* pb  = (const float*)d_in[15];
  const int* stid = (const int*)d_in[16];
  const int* sdiw = (const int*)d_in[17];
  const int* ttid = (const int*)d_in[18];
  const int* tdiw = (const int*)d_in[19];
  float* out = (float*)d_out;

  float* wp = (float*)d_ws;
  float* hbuf = wp; wp += (size_t)64*BNP;
  float* zh63 = wp; wp += BNP + 64;
  float* rbuf = wp; wp += (size_t)64*BNP;
  float* nv1A = wp; wp += (size_t)NST*DD*BNP;
  float* nv2A = wp; wp += (size_t)NST*DD*BNP;
  float* go   = wp; wp += BN + 64;
  unsigned short* egS = (unsigned short*)wp; wp += 163840;  // 10*2*4*4*128*8 = 327680 shorts
  unsigned short* dgS = (unsigned short*)wp; wp += 163840;
  unsigned short* euS = (unsigned short*)wp; wp += 81920;   // 10*2*4*4*64*8 = 163840 shorts
  unsigned short* duS = (unsigned short*)wp; wp += 81920;
  float* egA = wp; wp += 3840;   // 10*3*128
  float* dgA = wp; wp += 3840;
  float* euA = wp; wp += 1920;   // 10*3*64
  float* duA = wp; wp += 1920;
  unsigned short* XsH = (unsigned short*)wp; wp += 1835008; // 32b*14mt*16KB
  unsigned short* XsZ = (unsigned short*)wp; wp += 1835008;

  hipMemsetAsync(hbuf, 0, sizeof(float)*(size_t)64*BNP, stream);
  hipMemsetAsync(go, 0, sizeof(float)*(BN+64), stream);
  hipMemsetAsync(XsH, 0, (size_t)BB*NT*16384, stream);
  hipMemsetAsync(XsZ, 0, (size_t)BB*NT*16384, stream);

  wsplit_kernel<<<1280,256,0,stream>>>(egW, egb, 128, egS);   // 327680 elems
  wsplit_kernel<<<1280,256,0,stream>>>(dgW, dgb, 128, dgS);
  wsplit_kernel<<<640,256,0,stream>>>(euW, eub, 64, euS);     // 163840 elems
  wsplit_kernel<<<640,256,0,stream>>>(duW, dub, 64, duS);
  waux_kernel<<<15,256,0,stream>>>(egW, egb, 128, egA);
  waux_kernel<<<15,256,0,stream>>>(dgW, dgb, 128, dgA);
  waux_kernel<<<8,256,0,stream>>>(euW, eub, 64, euA);
  waux_kernel<<<8,256,0,stream>>>(duW, dub, 64, duA);

  dim3 pgrid(111, NST);
  prep_all<<<pgrid,256,0,stream>>>(tid1,tid2,diw1,diw2,node_emb,stid,sdiw,ttid,tdiw,src_vals,nv1A,nv2A,XsH,XsZ);

  dim3 fgrid(NT, BB);
  for (int t = 0; t < TSRC; ++t) {
    const float* n1 = nv1A + (size_t)t*DD*BNP;
    const float* n2 = nv2A + (size_t)t*DD*BNP;
    attn_gate<<<fgrid,256,0,stream>>>(n1,n2,XsH,hbuf,egS,egA,rbuf,XsZ,zh63);
    int xnm = (t < TSRC-1) ? 1 : 2;
    attn_upd<<<fgrid,256,0,stream>>>(n1,n2,XsZ,zh63,hbuf,euS,euA,rbuf,0,pW,pb,go,out,XsH,t,src_vals,xnm,t+1,XsZ);
  }
  for (int t = 0; t < HORZ; ++t) {
    const float* n1 = nv1A + (size_t)(TSRC+t)*DD*BNP;
    const float* n2 = nv2A + (size_t)(TSRC+t)*DD*BNP;
    attn_gate<<<fgrid,256,0,stream>>>(n1,n2,XsH,hbuf,dgS,dgA,rbuf,XsZ,zh63);
    int xnm = (t < HORZ-1) ? 3 : 0;
    attn_upd<<<fgrid,256,0,stream>>>(n1,n2,XsZ,zh63,hbuf,duS,duA,rbuf,1,pW,pb,go,out,XsH,t,src_vals,xnm,0,XsZ);
  }
}

// Round 11
// 4369.264 us; speedup vs baseline: 1.2585x; 1.2585x over previous
//
#include <hip/hip_runtime.h>

#define BB 32
#define TSRC 12
#define HORZ 12
#define NN 883
#define DD 10
#define HH 64
#define BN (BB*NN)     // 28256
#define BNP 28288      // 64-aligned stride
#define KF 5           // gate/upd MFMA K-frags: K=160. k-map: 0=x, 1..64=h, 65=bias, 66..130=ax, 131..159=0
#define NT 14          // ceil(NN/64) m-tiles per b
#define NST (TSRC+HORZ)

typedef __attribute__((ext_vector_type(8))) short short8;
typedef __attribute__((ext_vector_type(4))) float f32x4;

static __device__ __forceinline__ float sigmf(float x) { return 1.f/(1.f + __expf(-x)); }
static __device__ __forceinline__ float tanh_fast(float x) {
  float e = __expf(2.f*x);
  return (e - 1.f) / (e + 1.f);
}
static __device__ __forceinline__ unsigned int bf_hi(float f) {
  unsigned int u = __float_as_uint(f);
  return (u + 0x7fffu + ((u >> 16) & 1u)) >> 16;
}
static __device__ __forceinline__ float bf_f(unsigned int h) {
  return __uint_as_float(h << 16);
}
// global->LDS async 16B/lane; explicit addrspace casts (builtin requires as1/as3 pointers)
static __device__ __forceinline__ void lds_load16(const void* g, void* l) {
  __builtin_amdgcn_global_load_lds(
      (const __attribute__((address_space(1))) void*)g,
      (__attribute__((address_space(3))) void*)l, 16, 0, 0);
}

// XCD-chunked block swizzle: hw assigns wg->XCD by (linear id % 8); choose (b, rtile)
// so all NT tiles of one b share an XCD -> Xs/nv/W re-reads become L2 hits.
static __device__ __forceinline__ void swz_block(int& b, int& rt) {
  int lin = blockIdx.x + blockIdx.y*NT;
  int c = lin & 7, q = lin >> 3;
  b = c + ((q/NT) << 3);
  rt = q - (q/NT)*NT;
}

// Xs chunk layout (per (b, mtile), 16384 B = 8192 shorts):
//   logical short (hl, c, ms): byte = hl*8192 + c*128 + ms*2, stored at byte ^ ((c&7)<<4)
//   c=0 -> x column; c=1..63 -> h/zh rows 0..62. Row 63 kept as fp32 (h / zh63).
static __device__ __forceinline__ void xs_store(unsigned short* chunk, int c, int mm2, float v) {
  int p0 = (c*128 + (mm2 ^ ((c & 7) << 4))) >> 1;
  unsigned int hi = bf_hi(v);
  chunk[p0] = (unsigned short)hi;
  chunk[p0 + 4096] = (unsigned short)bf_hi(v - bf_f(hi));
}

// ---------------- prep_all: nvAll[24][10][BNP] once; x0 columns for step 0 ----------------
__global__ __launch_bounds__(256) void prep_all(
    const float* __restrict__ tidE1, const float* __restrict__ tidE2,
    const float* __restrict__ diwE1, const float* __restrict__ diwE2,
    const float* __restrict__ nodeE,
    const int* __restrict__ stid, const int* __restrict__ sdiw,
    const int* __restrict__ ttid, const int* __restrict__ tdiw,
    const float* __restrict__ xsrc,
    float* __restrict__ nv1A, float* __restrict__ nv2A,
    unsigned short* __restrict__ XsH, unsigned short* __restrict__ XsZ)
{
  int i = blockIdx.x*256 + threadIdx.x;
  if (i >= BN) return;
  int st = blockIdx.y;
  int b = i / NN, n = i - b*NN;
  const int* tix = (st < TSRC) ? stid : ttid;
  const int* dix = (st < TSRC) ? sdiw : tdiw;
  int t = (st < TSRC) ? st : st - TSRC;
  int gi = (b*TSRC + t)*NN + n;   // tlen == 12 for both enc and dec
  int ti = tix[gi]*DD, di = dix[gi]*DD;
  int nE = n*DD;
  float* nv1T = nv1A + (size_t)st*DD*BNP;
  float* nv2T = nv2A + (size_t)st*DD*BNP;
#pragma unroll
  for (int d = 0; d < DD; ++d) {
    float E = nodeE[nE+d];
    nv1T[d*BNP+i] = tanh_fast(E * (tidE1[ti+d] * diwE1[di+d]));
    nv2T[d*BNP+i] = tanh_fast(E * (tidE2[ti+d] * diwE2[di+d]));
  }
  if (st == 0) {
    float xv = xsrc[gi];   // enc t=0
    size_t cb = ((size_t)(b*NT + (n >> 6)))*8192;
    int mm = n & 63;
    unsigned int hi = bf_hi(xv);
    unsigned short los = (unsigned short)bf_hi(xv - bf_f(hi));
    XsH[cb + mm] = (unsigned short)hi; XsH[cb + 4096 + mm] = los;
    XsZ[cb + mm] = (unsigned short)hi; XsZ[cb + 4096 + mm] = los;
  }
}

// ------- wsplit: W -> B-fragment-ordered split-bf16 Wf[d][hl][kf][quad][NO][8] -------
__global__ __launch_bounds__(256) void wsplit_kernel(
    const float* __restrict__ W, const float* __restrict__ bias,
    int NO, unsigned short* __restrict__ Wf)
{
  int i = blockIdx.x*256 + threadIdx.x;
  int total = DD*2*KF*4*NO*8;
  if (i >= total) return;
  int j = i & 7; int r = i >> 3;
  int o = r % NO; r /= NO;
  int quad = r & 3; r >>= 2;
  int kf = r % KF; r /= KF;
  int hl = r & 1; int d = r >> 1;
  int kk = kf*32 + quad*8 + j;
  float v = 0.f;
  if (kk <= 64)       v = W[(size_t)(d*130 + kk)*NO + o];
  else if (kk == 65)  v = bias[d*NO + o];
  else if (kk <= 130) v = W[(size_t)(d*130 + kk - 1)*NO + o];
  unsigned int hi = bf_hi(v);
  Wf[i] = (hl == 0) ? (unsigned short)hi : (unsigned short)bf_hi(v - bf_f(hi));
}

// =========================================================================
// Fused attention + GEMM kernels. grid (NT, BB), 256 threads, 3 blocks/CU.
// A-source (x/h/zh channels 0..63) comes from the block's OWN Xs chunk (split
// pairs bit-identical to the fp32 path); channel 64 from fp32 row63.
// x columns (c=0) are handed forward by attn_upd's epilogue (prep removed).
// =========================================================================

// ---------------- attn_gate: attn(h) -> gate GEMM (NO=128, 2 co-halves) ----------------
__global__ __launch_bounds__(256,3) void attn_gate(
    const float* __restrict__ nv1T, const float* __restrict__ nv2T,
    const unsigned short* __restrict__ Xs,   // XsH
    const float* __restrict__ h,             // h state (xcol row63, r63, z*h epilogue)
    const unsigned short* __restrict__ Wf,   // [10][2][KF][4][128][8]
    float* __restrict__ rbuf,
    unsigned short* __restrict__ XsZ, float* __restrict__ zh63)
{
  __shared__ float nv1s[DD][64];
  __shared__ float linv[64];
  __shared__ alignas(16) unsigned char U[46080];
  unsigned short* XT = (unsigned short*)U;
  unsigned short* PT = (unsigned short*)(U + 16384);
  float* nv2s = (float*)(U + 34816);
  float* xcolb = (float*)(U + 39936);
  int b, rt;
  swz_block(b, rt);
  int r0 = rt*64;
  int tid = threadIdx.x;
  int rg = tid >> 4, cg = tid & 15;
  int base = b*NN;
  int lane = tid & 63, lm = lane & 15, quad = lane >> 4;
  int w = tid >> 6, mp = w >> 1, np = w & 1;
  const unsigned short* XsB = Xs + (size_t)b*NT*8192;

  for (int idx = tid; idx < DD*64; idx += 256) {
    int d = idx >> 6, r = idx & 63;
    nv1s[d][r] = (r0 + r < NN) ? nv1T[d*BNP + base + r0 + r] : 0.f;
  }

  int4 xt[4];
  float nvr[3]; float xcr;
  {
    const int4* s0 = (const int4*)XsB;
#pragma unroll
    for (int i = 0; i < 4; ++i) xt[i] = s0[w*64 + lane + i*256];
#pragma unroll
    for (int i = 0; i < 3; ++i) {
      int idx = tid + i*256; float v = 0.f;
      if (idx < DD*64) { int d = idx>>6, m = idx&63; v = (m < NN) ? nv2T[d*BNP + base + m] : 0.f; }
      nvr[i] = v;
    }
    xcr = (tid < 64 && tid < NN) ? h[(size_t)63*BNP + base + tid] : 0.f;
#pragma unroll
    for (int i = 0; i < 4; ++i)
      *(int4*)((char*)XT + w*1024 + lane*16 + i*4096) = xt[i];
#pragma unroll
    for (int i = 0; i < 3; ++i) {
      int idx = tid + i*256;
      if (idx < DD*64) nv2s[idx] = nvr[i];
    }
    if (tid < 64) xcolb[tid] = xcr;
  }
  __syncthreads();

  f32x4 accv[2][2] = {};
  float acclp[4] = {}, acc5p[4] = {};

  for (int tI = 0; tI < NT; ++tI) {
    int cur = tI & 1, nxt = cur ^ 1;
    int m0 = tI*64, m0n = m0 + 64;
    bool hasn = tI < NT-1;
    if (hasn) {
      const int4* src = (const int4*)(XsB + (size_t)(tI+1)*8192);
#pragma unroll
      for (int i = 0; i < 4; ++i) xt[i] = src[w*64 + lane + i*256];
#pragma unroll
      for (int i = 0; i < 3; ++i) {
        int idx = tid + i*256; float v = 0.f;
        if (idx < DD*64) { int d = idx>>6, m = idx&63; v = (m0n + m < NN) ? nv2T[d*BNP + base + m0n + m] : 0.f; }
        nvr[i] = v;
      }
      xcr = (tid < 64 && m0n + tid < NN) ? h[(size_t)63*BNP + base + m0n + tid] : 0.f;
    }
    float s[4][4] = {};
#pragma unroll
    for (int d = 0; d < DD; ++d) {
      float4 a4 = *(const float4*)&nv1s[d][rg*4];
      float4 c4 = *(const float4*)&nv2s[cur*(DD*64) + d*64 + cg*4];
      const float* ap = (const float*)&a4;
      const float* cp = (const float*)&c4;
#pragma unroll
      for (int j = 0; j < 4; ++j)
#pragma unroll
        for (int jj = 0; jj < 4; ++jj)
          s[j][jj] += ap[j]*cp[jj];
    }
    int mvlim = NN - m0;
    float ev[4][4];
#pragma unroll
    for (int jj = 0; jj < 4; ++jj) {
      int m = cg*4 + jj;
      float xm = xcolb[cur*64 + m];
      bool okm = m < mvlim;
#pragma unroll
      for (int j = 0; j < 4; ++j) {
        float e = okm ? __expf(fmaxf(s[j][jj], 0.f)) : 0.f;
        ev[j][jj] = e;
        acclp[j] += e;
        acc5p[j] = fmaf(e, xm, acc5p[j]);
      }
    }
    {
      unsigned int* P1 = (unsigned int*)PT;
      unsigned int* P2 = (unsigned int*)(PT + 64*72);
#pragma unroll
      for (int j = 0; j < 4; ++j) {
        int r = rg*4 + j;
        unsigned int h0 = bf_hi(ev[j][0]), h1 = bf_hi(ev[j][1]), h2 = bf_hi(ev[j][2]), h3 = bf_hi(ev[j][3]);
        unsigned int l0 = bf_hi(ev[j][0]-bf_f(h0)), l1 = bf_hi(ev[j][1]-bf_f(h1));
        unsigned int l2 = bf_hi(ev[j][2]-bf_f(h2)), l3 = bf_hi(ev[j][3]-bf_f(h3));
        int dw = r*36 + cg*2;
        P1[dw] = h0 | (h1 << 16); P1[dw+1] = h2 | (h3 << 16);
        P2[dw] = l0 | (l1 << 16); P2[dw+1] = l2 | (l3 << 16);
      }
    }
    __syncthreads();
    {
      short8 Aa[2][2], Ab[2][2], Ba[2][2], Bb[2][2];
#pragma unroll
      for (int mt = 0; mt < 2; ++mt) {
        int r = mp*32 + mt*16 + lm;
#pragma unroll
        for (int kf = 0; kf < 2; ++kf) {
          Aa[mt][kf] = *(const short8*)&PT[r*72 + quad*8 + kf*32];
          Ab[mt][kf] = *(const short8*)&PT[64*72 + r*72 + quad*8 + kf*32];
        }
      }
#pragma unroll
      for (int ntl = 0; ntl < 2; ++ntl) {
        int c = np*32 + ntl*16 + lm;
        int swz = (c & 7) << 4;
        int cb0 = c*128 + quad*16;
#pragma unroll
        for (int kf = 0; kf < 2; ++kf) {
          int a = (cb0 + kf*64) ^ swz;
          Ba[ntl][kf] = *(const short8*)((const char*)XT + a);
          Bb[ntl][kf] = *(const short8*)((const char*)XT + a + 8192);
        }
      }
#pragma unroll
      for (int kf = 0; kf < 2; ++kf)
#pragma unroll
        for (int mt = 0; mt < 2; ++mt)
#pragma unroll
          for (int ntl = 0; ntl < 2; ++ntl) {
            accv[mt][ntl] = __builtin_amdgcn_mfma_f32_16x16x32_bf16(Aa[mt][kf], Ba[ntl][kf], accv[mt][ntl], 0,0,0);
            accv[mt][ntl] = __builtin_amdgcn_mfma_f32_16x16x32_bf16(Aa[mt][kf], Bb[ntl][kf], accv[mt][ntl], 0,0,0);
            accv[mt][ntl] = __builtin_amdgcn_mfma_f32_16x16x32_bf16(Ab[mt][kf], Ba[ntl][kf], accv[mt][ntl], 0,0,0);
          }
    }
    if (hasn) {
#pragma unroll
      for (int i = 0; i < 3; ++i) {
        int idx = tid + i*256;
        if (idx < DD*64) nv2s[nxt*(DD*64) + idx] = nvr[i];
      }
      if (tid < 64) xcolb[nxt*64 + tid] = xcr;
    }
    __syncthreads();
    if (hasn) {
#pragma unroll
      for (int i = 0; i < 4; ++i)
        *(int4*)((char*)XT + w*1024 + lane*16 + i*4096) = xt[i];
    }
  }
  // ---- A-source from own Xs chunk (split pairs bit-identical) + row63 fp32 ----
  int mrow_x = tid >> 2, ksub = tid & 3;
  int gmx = base + r0 + mrow_x;
  const unsigned short* chk_in = Xs + (size_t)(b*NT + rt)*8192;
  int mm2x = mrow_x*2;
  unsigned int pjh[9], pjl[9];
  {
    float r63v = h[(size_t)63*BNP + gmx];
    unsigned int h63 = bf_hi(r63v);
    unsigned int l63 = bf_hi(r63v - bf_f(h63));
#pragma unroll
    for (int i = 0; i < 9; ++i) {
      int kk = ksub*2 + 8*i;
      unsigned int h0 = 0, l0 = 0, h1 = 0, l1 = 0;
      if (kk <= 63) {
        int idx = (kk*128 + (mm2x ^ ((kk & 7) << 4))) >> 1;
        h0 = chk_in[idx]; l0 = chk_in[idx + 4096];
      } else if (kk == 64) { h0 = h63; l0 = l63; }
      int k1 = kk + 1;
      if (kk <= 62) {
        int idx1 = (k1*128 + (mm2x ^ ((k1 & 7) << 4))) >> 1;
        h1 = chk_in[idx1]; l1 = chk_in[idx1 + 4096];
      } else if (k1 == 65) { h1 = 0x3F80u; l1 = 0u; }
      pjh[i] = h0 | (h1 << 16);
      pjl[i] = l0 | (l1 << 16);
    }
  }
#pragma unroll
  for (int off = 1; off <= 8; off <<= 1)
#pragma unroll
    for (int j = 0; j < 4; ++j) {
      acclp[j] += __shfl_xor(acclp[j], off, 64);
      acc5p[j] += __shfl_xor(acc5p[j], off, 64);
    }
  __syncthreads();   // attn LDS dead
  {
    unsigned int* Z = (unsigned int*)(U + 36864);
    for (int idx = tid; idx < 2304; idx += 256) Z[idx] = 0;
  }
  __syncthreads();
  unsigned short* XA = (unsigned short*)U;
  if (cg == 0) {
#pragma unroll
    for (int j = 0; j < 4; ++j) {
      float li = 1.f / acclp[j];
      int r = rg*4 + j;
      linv[r] = li;
      float v = acc5p[j]*li;   // ax channel 64 -> kk=130 (kf4, kkl2)
      unsigned int hi = bf_hi(v);
      XA[(4*64 + r)*72 + 2] = (unsigned short)hi;
      XA[(4*64 + r)*72 + 32 + 2] = (unsigned short)bf_hi(v - bf_f(hi));
    }
  }
  __syncthreads();
  // ax scatter: kk=66+c from accv*li
#pragma unroll
  for (int mt = 0; mt < 2; ++mt) {
    int rbase = mp*32 + mt*16 + quad*4;
    float4 lv = *(const float4*)&linv[rbase];
    const float* lvp = (const float*)&lv;
#pragma unroll
    for (int ntl = 0; ntl < 2; ++ntl) {
      int c = np*32 + ntl*16 + lm;
      int kk = 66 + c;
      int kf = kk >> 5, kkl = kk & 31;
#pragma unroll
      for (int r4 = 0; r4 < 4; ++r4) {
        float v = accv[mt][ntl][r4] * lvp[r4];
        unsigned int hi = bf_hi(v);
        int p = (kf*64 + rbase + r4)*72 + kkl;
        XA[p] = (unsigned short)hi;
        XA[p + 32] = (unsigned short)bf_hi(v - bf_f(hi));
      }
    }
  }
  // x/h/bias fill (kk pairs 0..65) from prefetched chunk pairs
  {
    unsigned int* X1 = (unsigned int*)U;
#pragma unroll
    for (int i = 0; i < 9; ++i) {
      int kk = ksub*2 + 8*i;
      if (kk > 64) continue;
      int kf = kk >> 5, kkl = kk & 31;
      int dw = (kf*64 + mrow_x)*36 + (kkl >> 1);
      X1[dw] = pjh[i];
      X1[dw + 16] = pjl[i];
    }
  }
  __syncthreads();
  // A-frags to regs
  short8 A1[2][KF], A2[2][KF];
#pragma unroll
  for (int mt = 0; mt < 2; ++mt) {
    int mrow = mp*32 + mt*16 + lm;
#pragma unroll
    for (int kf = 0; kf < KF; ++kf) {
      A1[mt][kf] = *(const short8*)&XA[(kf*64 + mrow)*72 + quad*8];
      A2[mt][kf] = *(const short8*)&XA[(kf*64 + mrow)*72 + 32 + quad*8];
    }
  }
  __syncthreads();   // U becomes W buffers
  unsigned char* bufA = U;
  unsigned char* bufB = U + 20480;
  const int colb = np*32 + lm;
#pragma unroll 1
  for (int co = 0; co < 2; ++co) {
    int co0 = co*64;
    {
      const unsigned short* src = Wf + ((size_t)(w*5)*128 + co0)*8 + lane*8;
#pragma unroll
      for (int i = 0; i < 5; ++i)
        lds_load16(src + (size_t)i*128*8, bufA + (w*5+i)*1024);
    }
    f32x4 accO[2][2] = {};
#pragma unroll 1
    for (int d = 0; d < DD; ++d) {
      f32x4 td[2][2] = {};
      __syncthreads();
      {
        const unsigned short* src = Wf + ((size_t)((d*2+1)*20 + w*5)*128 + co0)*8 + lane*8;
#pragma unroll
        for (int i = 0; i < 5; ++i)
          lds_load16(src + (size_t)i*128*8, bufB + (w*5+i)*1024);
      }
#pragma unroll
      for (int kf = 0; kf < KF; ++kf) {
        int cb = ((kf*4 + quad)*64 + colb)*16;
#pragma unroll
        for (int ntl = 0; ntl < 2; ++ntl) {
          short8 Bh = *(const short8*)(bufA + cb + ntl*256);
          td[0][ntl] = __builtin_amdgcn_mfma_f32_16x16x32_bf16(A1[0][kf], Bh, td[0][ntl], 0,0,0);
          td[0][ntl] = __builtin_amdgcn_mfma_f32_16x16x32_bf16(A2[0][kf], Bh, td[0][ntl], 0,0,0);
          td[1][ntl] = __builtin_amdgcn_mfma_f32_16x16x32_bf16(A1[1][kf], Bh, td[1][ntl], 0,0,0);
          td[1][ntl] = __builtin_amdgcn_mfma_f32_16x16x32_bf16(A2[1][kf], Bh, td[1][ntl], 0,0,0);
        }
      }
      __syncthreads();
      if (d < DD-1) {
        const unsigned short* src = Wf + ((size_t)((d+1)*2*20 + w*5)*128 + co0)*8 + lane*8;
#pragma unroll
        for (int i = 0; i < 5; ++i)
          lds_load16(src + (size_t)i*128*8, bufA + (w*5+i)*1024);
      }
#pragma unroll
      for (int kf = 0; kf < KF; ++kf) {
        int cb = ((kf*4 + quad)*64 + colb)*16;
#pragma unroll
        for (int ntl = 0; ntl < 2; ++ntl) {
          short8 Bl = *(const short8*)(bufB + cb + ntl*256);
          td[0][ntl] = __builtin_amdgcn_mfma_f32_16x16x32_bf16(A1[0][kf], Bl, td[0][ntl], 0,0,0);
          td[1][ntl] = __builtin_amdgcn_mfma_f32_16x16x32_bf16(A1[1][kf], Bl, td[1][ntl], 0,0,0);
        }
      }
#pragma unroll
      for (int mt = 0; mt < 2; ++mt) {
        float4 nv4 = *(const float4*)&nv1s[d][mp*32 + mt*16 + quad*4];
        const float* nvp = (const float*)&nv4;
#pragma unroll
        for (int ntl = 0; ntl < 2; ++ntl)
#pragma unroll
          for (int r = 0; r < 4; ++r)
            accO[mt][ntl][r] += nvp[r] * td[mt][ntl][r];
      }
    }
    float* CT = (float*)U;
    __syncthreads();
#pragma unroll
    for (int mt = 0; mt < 2; ++mt)
#pragma unroll
      for (int ntl = 0; ntl < 2; ++ntl)
#pragma unroll
        for (int r = 0; r < 4; ++r)
          CT[(mp*32 + mt*16 + quad*4 + r)*67 + np*32 + ntl*16 + lm] = accO[mt][ntl][r];
    __syncthreads();
    {
      int mm = tid & 63, og = tid >> 6;
      int n = r0 + mm;
      int gm = base + n;
      bool okn = n < NN;
      if (co == 0) {
        unsigned short* chk = XsZ + ((size_t)(b*NT + rt))*8192;
        int mm2 = mm*2;
        for (int j = 0; j < 16; ++j) {
          int o = og*16 + j;
          float z = sigmf(CT[mm*67 + o]);
          float zhv = z * h[(size_t)o*BNP + gm];
          if (okn) {
            if (o < 63) xs_store(chk, o + 1, mm2, zhv);
            else zh63[gm] = zhv;
          }
        }
      } else {
        for (int j = 0; j < 16; ++j) {
          int o = og*16 + j;
          if (okn) rbuf[(size_t)o*BNP + gm] = sigmf(CT[mm*67 + o]);
        }
      }
    }
    __syncthreads();  // CT reads done before next co's staging
  }
}

// ---------------- attn_upd: attn(zh) -> upd GEMM (NO=64); dec: fused proj ----------------
// xnmode: 0=none, 1=write src_vals[xnt] as next x column, 2=write zeros, 3=write computed go (dec)
__global__ __launch_bounds__(256,3) void attn_upd(
    const float* __restrict__ nv1T, const float* __restrict__ nv2T,
    const unsigned short* __restrict__ Xs,   // XsZ (B-stream + A-source chunk)
    const float* __restrict__ zh63,          // zh row 63 fp32 (xcol + A channel 64)
    float* __restrict__ hstate,              // h (read/modify/write)
    const unsigned short* __restrict__ Wf,   // [10][2][KF][4][64][8]
    const float* __restrict__ rbuf,
    int dec, const float* __restrict__ pW, const float* __restrict__ pb,
    float* __restrict__ go, float* __restrict__ dout,
    unsigned short* __restrict__ XsH, int t,
    const float* __restrict__ xsrc, int xnmode, int xnt,
    unsigned short* __restrict__ XsZm)
{
  __shared__ float nv1s[DD][64];
  __shared__ float linv[64];
  __shared__ alignas(16) unsigned char U[46080];
  unsigned short* XT = (unsigned short*)U;
  unsigned short* PT = (unsigned short*)(U + 16384);
  float* nv2s = (float*)(U + 34816);
  float* xcolb = (float*)(U + 39936);
  int b, rt;
  swz_block(b, rt);
  int r0 = rt*64;
  int tid = threadIdx.x;
  int rg = tid >> 4, cg = tid & 15;
  int base = b*NN;
  int lane = tid & 63, lm = lane & 15, quad = lane >> 4;
  int w = tid >> 6, mp = w >> 1, np = w & 1;
  const unsigned short* XsB = Xs + (size_t)b*NT*8192;

  for (int idx = tid; idx < DD*64; idx += 256) {
    int d = idx >> 6, r = idx & 63;
    nv1s[d][r] = (r0 + r < NN) ? nv1T[d*BNP + base + r0 + r] : 0.f;
  }

  int4 xt[4];
  float nvr[3]; float xcr;
  {
    const int4* s0 = (const int4*)XsB;
#pragma unroll
    for (int i = 0; i < 4; ++i) xt[i] = s0[w*64 + lane + i*256];
#pragma unroll
    for (int i = 0; i < 3; ++i) {
      int idx = tid + i*256; float v = 0.f;
      if (idx < DD*64) { int d = idx>>6, m = idx&63; v = (m < NN) ? nv2T[d*BNP + base + m] : 0.f; }
      nvr[i] = v;
    }
    xcr = (tid < 64 && tid < NN) ? zh63[base + tid] : 0.f;
#pragma unroll
    for (int i = 0; i < 4; ++i)
      *(int4*)((char*)XT + w*1024 + lane*16 + i*4096) = xt[i];
#pragma unroll
    for (int i = 0; i < 3; ++i) {
      int idx = tid + i*256;
      if (idx < DD*64) nv2s[idx] = nvr[i];
    }
    if (tid < 64) xcolb[tid] = xcr;
  }
  __syncthreads();

  f32x4 accv[2][2] = {};
  float acclp[4] = {}, acc5p[4] = {};

  for (int tI = 0; tI < NT; ++tI) {
    int cur = tI & 1, nxt = cur ^ 1;
    int m0 = tI*64, m0n = m0 + 64;
    bool hasn = tI < NT-1;
    if (hasn) {
      const int4* src = (const int4*)(XsB + (size_t)(tI+1)*8192);
#pragma unroll
      for (int i = 0; i < 4; ++i) xt[i] = src[w*64 + lane + i*256];
#pragma unroll
      for (int i = 0; i < 3; ++i) {
        int idx = tid + i*256; float v = 0.f;
        if (idx < DD*64) { int d = idx>>6, m = idx&63; v = (m0n + m < NN) ? nv2T[d*BNP + base + m0n + m] : 0.f; }
        nvr[i] = v;
      }
      xcr = (tid < 64 && m0n + tid < NN) ? zh63[base + m0n + tid] : 0.f;
    }
    float s[4][4] = {};
#pragma unroll
    for (int d = 0; d < DD; ++d) {
      float4 a4 = *(const float4*)&nv1s[d][rg*4];
      float4 c4 = *(const float4*)&nv2s[cur*(DD*64) + d*64 + cg*4];
      const float* ap = (const float*)&a4;
      const float* cp = (const float*)&c4;
#pragma unroll
      for (int j = 0; j < 4; ++j)
#pragma unroll
        for (int jj = 0; jj < 4; ++jj)
          s[j][jj] += ap[j]*cp[jj];
    }
    int mvlim = NN - m0;
    float ev[4][4];
#pragma unroll
    for (int jj = 0; jj < 4; ++jj) {
      int m = cg*4 + jj;
      float xm = xcolb[cur*64 + m];
      bool okm = m < mvlim;
#pragma unroll
      for (int j = 0; j < 4; ++j) {
        float e = okm ? __expf(fmaxf(s[j][jj], 0.f)) : 0.f;
        ev[j][jj] = e;
        acclp[j] += e;
        acc5p[j] = fmaf(e, xm, acc5p[j]);
      }
    }
    {
      unsigned int* P1 = (unsigned int*)PT;
      unsigned int* P2 = (unsigned int*)(PT + 64*72);
#pragma unroll
      for (int j = 0; j < 4; ++j) {
        int r = rg*4 + j;
        unsigned int h0 = bf_hi(ev[j][0]), h1 = bf_hi(ev[j][1]), h2 = bf_hi(ev[j][2]), h3 = bf_hi(ev[j][3]);
        unsigned int l0 = bf_hi(ev[j][0]-bf_f(h0)), l1 = bf_hi(ev[j][1]-bf_f(h1));
        unsigned int l2 = bf_hi(ev[j][2]-bf_f(h2)), l3 = bf_hi(ev[j][3]-bf_f(h3));
        int dw = r*36 + cg*2;
        P1[dw] = h0 | (h1 << 16); P1[dw+1] = h2 | (h3 << 16);
        P2[dw] = l0 | (l1 << 16); P2[dw+1] = l2 | (l3 << 16);
      }
    }
    __syncthreads();
    {
      short8 Aa[2][2], Ab[2][2], Ba[2][2], Bb[2][2];
#pragma unroll
      for (int mt = 0; mt < 2; ++mt) {
        int r = mp*32 + mt*16 + lm;
#pragma unroll
        for (int kf = 0; kf < 2; ++kf) {
          Aa[mt][kf] = *(const short8*)&PT[r*72 + quad*8 + kf*32];
          Ab[mt][kf] = *(const short8*)&PT[64*72 + r*72 + quad*8 + kf*32];
        }
      }
#pragma unroll
      for (int ntl = 0; ntl < 2; ++ntl) {
        int c = np*32 + ntl*16 + lm;
        int swz = (c & 7) << 4;
        int cb0 = c*128 + quad*16;
#pragma unroll
        for (int kf = 0; kf < 2; ++kf) {
          int a = (cb0 + kf*64) ^ swz;
          Ba[ntl][kf] = *(const short8*)((const char*)XT + a);
          Bb[ntl][kf] = *(const short8*)((const char*)XT + a + 8192);
        }
      }
#pragma unroll
      for (int kf = 0; kf < 2; ++kf)
#pragma unroll
        for (int mt = 0; mt < 2; ++mt)
#pragma unroll
          for (int ntl = 0; ntl < 2; ++ntl) {
            accv[mt][ntl] = __builtin_amdgcn_mfma_f32_16x16x32_bf16(Aa[mt][kf], Ba[ntl][kf], accv[mt][ntl], 0,0,0);
            accv[mt][ntl] = __builtin_amdgcn_mfma_f32_16x16x32_bf16(Aa[mt][kf], Bb[ntl][kf], accv[mt][ntl], 0,0,0);
            accv[mt][ntl] = __builtin_amdgcn_mfma_f32_16x16x32_bf16(Ab[mt][kf], Ba[ntl][kf], accv[mt][ntl], 0,0,0);
          }
    }
    if (hasn) {
#pragma unroll
      for (int i = 0; i < 3; ++i) {
        int idx = tid + i*256;
        if (idx < DD*64) nv2s[nxt*(DD*64) + idx] = nvr[i];
      }
      if (tid < 64) xcolb[nxt*64 + tid] = xcr;
    }
    __syncthreads();
    if (hasn) {
#pragma unroll
      for (int i = 0; i < 4; ++i)
        *(int4*)((char*)XT + w*1024 + lane*16 + i*4096) = xt[i];
    }
  }
  // ---- A-source from own XsZ chunk + zh row63 fp32 ----
  int mrow_x = tid >> 2, ksub = tid & 3;
  int gmx = base + r0 + mrow_x;
  const unsigned short* chk_in = Xs + (size_t)(b*NT + rt)*8192;
  int mm2x = mrow_x*2;
  unsigned int pjh[9], pjl[9];
  {
    float r63v = zh63[gmx];
    unsigned int h63 = bf_hi(r63v);
    unsigned int l63 = bf_hi(r63v - bf_f(h63));
#pragma unroll
    for (int i = 0; i < 9; ++i) {
      int kk = ksub*2 + 8*i;
      unsigned int h0 = 0, l0 = 0, h1 = 0, l1 = 0;
      if (kk <= 63) {
        int idx = (kk*128 + (mm2x ^ ((kk & 7) << 4))) >> 1;
        h0 = chk_in[idx]; l0 = chk_in[idx + 4096];
      } else if (kk == 64) { h0 = h63; l0 = l63; }
      int k1 = kk + 1;
      if (kk <= 62) {
        int idx1 = (k1*128 + (mm2x ^ ((k1 & 7) << 4))) >> 1;
        h1 = chk_in[idx1]; l1 = chk_in[idx1 + 4096];
      } else if (k1 == 65) { h1 = 0x3F80u; l1 = 0u; }
      pjh[i] = h0 | (h1 << 16);
      pjl[i] = l0 | (l1 << 16);
    }
  }
#pragma unroll
  for (int off = 1; off <= 8; off <<= 1)
#pragma unroll
    for (int j = 0; j < 4; ++j) {
      acclp[j] += __shfl_xor(acclp[j], off, 64);
      acc5p[j] += __shfl_xor(acc5p[j], off, 64);
    }
  __syncthreads();
  {
    unsigned int* Z = (unsigned int*)(U + 36864);
    for (int idx = tid; idx < 2304; idx += 256) Z[idx] = 0;
  }
  __syncthreads();
  unsigned short* XA = (unsigned short*)U;
  if (cg == 0) {
#pragma unroll
    for (int j = 0; j < 4; ++j) {
      float li = 1.f / acclp[j];
      int r = rg*4 + j;
      linv[r] = li;
      float v = acc5p[j]*li;
      unsigned int hi = bf_hi(v);
      XA[(4*64 + r)*72 + 2] = (unsigned short)hi;
      XA[(4*64 + r)*72 + 32 + 2] = (unsigned short)bf_hi(v - bf_f(hi));
    }
  }
  __syncthreads();
#pragma unroll
  for (int mt = 0; mt < 2; ++mt) {
    int rbase = mp*32 + mt*16 + quad*4;
    float4 lv = *(const float4*)&linv[rbase];
    const float* lvp = (const float*)&lv;
#pragma unroll
    for (int ntl = 0; ntl < 2; ++ntl) {
      int c = np*32 + ntl*16 + lm;
      int kk = 66 + c;
      int kf = kk >> 5, kkl = kk & 31;
#pragma unroll
      for (int r4 = 0; r4 < 4; ++r4) {
        float v = accv[mt][ntl][r4] * lvp[r4];
        unsigned int hi = bf_hi(v);
        int p = (kf*64 + rbase + r4)*72 + kkl;
        XA[p] = (unsigned short)hi;
        XA[p + 32] = (unsigned short)bf_hi(v - bf_f(hi));
      }
    }
  }
  {
    unsigned int* X1 = (unsigned int*)U;
#pragma unroll
    for (int i = 0; i < 9; ++i) {
      int kk = ksub*2 + 8*i;
      if (kk > 64) continue;
      int kf = kk >> 5, kkl = kk & 31;
      int dw = (kf*64 + mrow_x)*36 + (kkl >> 1);
      X1[dw] = pjh[i];
      X1[dw + 16] = pjl[i];
    }
  }
  __syncthreads();
  short8 A1[2][KF], A2[2][KF];
#pragma unroll
  for (int mt = 0; mt < 2; ++mt) {
    int mrow = mp*32 + mt*16 + lm;
#pragma unroll
    for (int kf = 0; kf < KF; ++kf) {
      A1[mt][kf] = *(const short8*)&XA[(kf*64 + mrow)*72 + quad*8];
      A2[mt][kf] = *(const short8*)&XA[(kf*64 + mrow)*72 + 32 + quad*8];
    }
  }
  __syncthreads();
  unsigned char* bufA = U;
  unsigned char* bufB = U + 20480;
  const int colb = np*32 + lm;
  {
    const unsigned short* src = Wf + (size_t)(w*5)*64*8 + lane*8;
#pragma unroll
    for (int i = 0; i < 5; ++i)
      lds_load16(src + (size_t)i*64*8, bufA + (w*5+i)*1024);
  }
  f32x4 accO[2][2] = {};
#pragma unroll 1
  for (int d = 0; d < DD; ++d) {
    f32x4 td[2][2] = {};
    __syncthreads();
    {
      const unsigned short* src = Wf + (size_t)((d*2+1)*20 + w*5)*64*8 + lane*8;
#pragma unroll
      for (int i = 0; i < 5; ++i)
        lds_load16(src + (size_t)i*64*8, bufB + (w*5+i)*1024);
    }
#pragma unroll
    for (int kf = 0; kf < KF; ++kf) {
      int cb = ((kf*4 + quad)*64 + colb)*16;
#pragma unroll
      for (int ntl = 0; ntl < 2; ++ntl) {
        short8 Bh = *(const short8*)(bufA + cb + ntl*256);
        td[0][ntl] = __builtin_amdgcn_mfma_f32_16x16x32_bf16(A1[0][kf], Bh, td[0][ntl], 0,0,0);
        td[0][ntl] = __builtin_amdgcn_mfma_f32_16x16x32_bf16(A2[0][kf], Bh, td[0][ntl], 0,0,0);
        td[1][ntl] = __builtin_amdgcn_mfma_f32_16x16x32_bf16(A1[1][kf], Bh, td[1][ntl], 0,0,0);
        td[1][ntl] = __builtin_amdgcn_mfma_f32_16x16x32_bf16(A2[1][kf], Bh, td[1][ntl], 0,0,0);
      }
    }
    __syncthreads();
    if (d < DD-1) {
      const unsigned short* src = Wf + (size_t)((d+1)*2*20 + w*5)*64*8 + lane*8;
#pragma unroll
      for (int i = 0; i < 5; ++i)
        lds_load16(src + (size_t)i*64*8, bufA + (w*5+i)*1024);
    }
#pragma unroll
    for (int kf = 0; kf < KF; ++kf) {
      int cb = ((kf*4 + quad)*64 + colb)*16;
#pragma unroll
      for (int ntl = 0; ntl < 2; ++ntl) {
        short8 Bl = *(const short8*)(bufB + cb + ntl*256);
        td[0][ntl] = __builtin_amdgcn_mfma_f32_16x16x32_bf16(A1[0][kf], Bl, td[0][ntl], 0,0,0);
        td[1][ntl] = __builtin_amdgcn_mfma_f32_16x16x32_bf16(A1[1][kf], Bl, td[1][ntl], 0,0,0);
      }
    }
#pragma unroll
    for (int mt = 0; mt < 2; ++mt) {
      float4 nv4 = *(const float4*)&nv1s[d][mp*32 + mt*16 + quad*4];
      const float* nvp = (const float*)&nv4;
#pragma unroll
      for (int ntl = 0; ntl < 2; ++ntl)
#pragma unroll
        for (int r = 0; r < 4; ++r)
          accO[mt][ntl][r] += nvp[r] * td[mt][ntl][r];
    }
  }
  float* CT = (float*)U;
  __syncthreads();
#pragma unroll
  for (int mt = 0; mt < 2; ++mt)
#pragma unroll
    for (int ntl = 0; ntl < 2; ++ntl)
#pragma unroll
      for (int r = 0; r < 4; ++r)
        CT[(mp*32 + mt*16 + quad*4 + r)*67 + np*32 + ntl*16 + lm] = accO[mt][ntl][r];
  __syncthreads();
  {
    int mm = tid & 63, og = tid >> 6;
    int n = r0 + mm;
    int gm = base + n;
    bool okn = n < NN;
    unsigned short* chk = XsH + ((size_t)(b*NT + rt))*8192;
    int mm2 = mm*2;
    float pp = 0.f;
    float sval = 0.f;
    for (int j = 0; j < 16; ++j) {
      int o = og*16 + j;
      float hc = tanhf(CT[mm*67 + o]);
      float r = rbuf[(size_t)o*BNP + gm];
      float hv = hstate[(size_t)o*BNP + gm];
      float hn = r*hv + (1.f - r)*hc;
      if (okn) {
        hstate[(size_t)o*BNP + gm] = hn;
        if (o < 63) xs_store(chk, o + 1, mm2, hn);
      }
      if (dec) pp = fmaf(hn, pW[o], pp);
    }
    if (dec) {
      float* PS = CT + 64*67;
      __syncthreads();
      PS[mm*4 + og] = pp;
      __syncthreads();
      if (tid < 64) {
        int n2 = r0 + tid;
        if (n2 < NN) {
          float s = pb[0] + PS[tid*4] + PS[tid*4+1] + PS[tid*4+2] + PS[tid*4+3];
          go[base + n2] = s;
          dout[(b*HORZ + t)*NN + n2] = s;
          sval = s;
        }
      }
    }
    // ---- next-step x-column handoff (replaces per-step prep) ----
    if (xnmode) {
      if (tid < 64) {
        int n2 = r0 + tid;
        if (n2 < NN) {
          float xn;
          if (xnmode == 1)      xn = xsrc[(b*TSRC + xnt)*NN + n2];
          else if (xnmode == 2) xn = 0.f;
          else                  xn = sval;   // dec: freshly computed go
          unsigned int hix = bf_hi(xn);
          unsigned short lox = (unsigned short)bf_hi(xn - bf_f(hix));
          unsigned short* cH = XsH + ((size_t)(b*NT + rt))*8192;
          unsigned short* cZ = XsZm + ((size_t)(b*NT + rt))*8192;
          cH[tid] = (unsigned short)hix; cH[4096 + tid] = lox;
          cZ[tid] = (unsigned short)hix; cZ[4096 + tid] = lox;
        }
      }
    }
  }
}

extern "C" void kernel_launch(void* const* d_in, const int* in_sizes, int n_in,
                              void* d_out, int out_size, void* d_ws, size_t ws_size,
                              hipStream_t stream) {
  (void)in_sizes; (void)n_in; (void)out_size; (void)ws_size;
  const float* src_vals = (const float*)d_in[0];
  const float* node_emb = (const float*)d_in[1];
  const float* tid1 = (const float*)d_in[2];
  const float* tid2 = (const float*)d_in[3];
  const float* diw1 = (const float*)d_in[4];
  const float* diw2 = (const float*)d_in[5];
  const float* egW = (const float*)d_in[6];
  const float* egb = (const float*)d_in[7];
  const float* euW = (const float*)d_in[8];
  const float* eub = (const float*)d_in[9];
  const float* dgW = (const float*)d_in[10];
  const float* dgb = (const float*)d_in[11];
  const float* duW = (const float*)d_in[12];
  const float* dub = (const float*)d_in[13];
  const float* pW  = (const float*)d_in[14];
  const float* pb  = (const float*)d_in[15];
  const int* stid = (const int*)d_in[16];
  const int* sdiw = (const int*)d_in[17];
  const int* ttid = (const int*)d_in[18];
  const int* tdiw = (const int*)d_in[19];
  float* out = (float*)d_out;

  float* wp = (float*)d_ws;
  float* hbuf = wp; wp += (size_t)64*BNP;
  float* zh63 = wp; wp += BNP + 64;
  float* rbuf = wp; wp += (size_t)64*BNP;
  float* nv1A = wp; wp += (size_t)NST*DD*BNP;   // 24 steps precomputed
  float* nv2A = wp; wp += (size_t)NST*DD*BNP;
  float* go   = wp; wp += BN + 64;
  unsigned short* egS = (unsigned short*)wp; wp += 204800;  // 10*2*5*4*128*8 shorts
  unsigned short* dgS = (unsigned short*)wp; wp += 204800;
  unsigned short* euS = (unsigned short*)wp; wp += 102400;  // 10*2*5*4*64*8 shorts
  unsigned short* duS = (unsigned short*)wp; wp += 102400;
  unsigned short* XsH = (unsigned short*)wp; wp += 1835008; // 32b*14mt*16KB = 7.34MB
  unsigned short* XsZ = (unsigned short*)wp; wp += 1835008;

  hipMemsetAsync(hbuf, 0, sizeof(float)*(size_t)64*BNP, stream);
  hipMemsetAsync(go, 0, sizeof(float)*(BN+64), stream);
  hipMemsetAsync(XsH, 0, (size_t)BB*NT*16384, stream);
  hipMemsetAsync(XsZ, 0, (size_t)BB*NT*16384, stream);

  wsplit_kernel<<<1600,256,0,stream>>>(egW, egb, 128, egS);
  wsplit_kernel<<<1600,256,0,stream>>>(dgW, dgb, 128, dgS);
  wsplit_kernel<<<800,256,0,stream>>>(euW, eub, 64, euS);
  wsplit_kernel<<<800,256,0,stream>>>(duW, dub, 64, duS);

  dim3 pgrid(111, NST);
  prep_all<<<pgrid,256,0,stream>>>(tid1,tid2,diw1,diw2,node_emb,stid,sdiw,ttid,tdiw,src_vals,nv1A,nv2A,XsH,XsZ);

  dim3 fgrid(NT, BB);
  for (int t = 0; t < TSRC; ++t) {
    const float* n1 = nv1A + (size_t)t*DD*BNP;
    const float* n2 = nv2A + (size_t)t*DD*BNP;
    attn_gate<<<fgrid,256,0,stream>>>(n1,n2,XsH,hbuf,egS,rbuf,XsZ,zh63);
    int xnm = (t < TSRC-1) ? 1 : 2;
    attn_upd<<<fgrid,256,0,stream>>>(n1,n2,XsZ,zh63,hbuf,euS,rbuf,0,pW,pb,go,out,XsH,t,src_vals,xnm,t+1,XsZ);
  }
  for (int t = 0; t < HORZ; ++t) {
    const float* n1 = nv1A + (size_t)(TSRC+t)*DD*BNP;
    const float* n2 = nv2A + (size_t)(TSRC+t)*DD*BNP;
    attn_gate<<<fgrid,256,0,stream>>>(n1,n2,XsH,hbuf,dgS,rbuf,XsZ,zh63);
    int xnm = (t < HORZ-1) ? 3 : 0;
    attn_upd<<<fgrid,256,0,stream>>>(n1,n2,XsZ,zh63,hbuf,duS,rbuf,1,pW,pb,go,out,XsH,t,src_vals,xnm,0,XsZ);
  }
}